// Round 1
// 681.444 us; speedup vs baseline: 1.2672x; 1.2672x over previous
//
#include <hip/hip_runtime.h>

// CausalWindowedAttention: B=2,H=16,S=2048,D=64, window=256, temp=8
// Outputs: out [B,H,S,D] fp32, attn [B,H,S,S] fp32 (concatenated in d_out).
//
// R1 restructure vs previous version:
//  - PV/QK row-split across waves (wave wv owns rows 4wv..4wv+3): kills po[]
//    partial buffer + cross-wave reduce phase. LDS 59392 -> 50112 B => 3
//    blocks/CU (was 2), launch_bounds(256,3).
//  - XCD-chunked block swizzle: consecutive tiles share 256/272 of the K/V
//    window; chunking keeps one bh's ~1MB K/V in a single XCD L2.
//  - attn store split: zero region (87.5%) issued right after last global
//    load consumption with zero VALU/LDS cost, drains under P3 compute
//    (P3/P4 have no vmcnt waits). P4 writes only the ~65/512 band groups.

#define S_LEN 2048
#define DHEAD 64
#define TQ 16
#define UEXT 272      // staged key-column extent per block: j in [i0-256, i0+16)
#define KV_STRIDE 72  // halfs; 144 B rows (16B aligned)
#define SC_STRIDE 276 // halfs; 552 B rows (8B aligned)

typedef float     f4v __attribute__((ext_vector_type(4)));
typedef _Float16  h2v __attribute__((ext_vector_type(2)));
typedef _Float16  h4v __attribute__((ext_vector_type(4)));

__device__ __forceinline__ float dot2f(float aBits, float bBits, float c) {
#if __has_builtin(__builtin_amdgcn_fdot2)
  return __builtin_amdgcn_fdot2(__builtin_bit_cast(h2v, aBits),
                                __builtin_bit_cast(h2v, bBits), c, false);
#else
  h2v a = __builtin_bit_cast(h2v, aBits);
  h2v b = __builtin_bit_cast(h2v, bBits);
  return c + (float)a.x * (float)b.x + (float)a.y * (float)b.y;
#endif
}

__global__ __launch_bounds__(256, 3)
void cwa_kernel(const float* __restrict__ q, const float* __restrict__ k,
                const float* __restrict__ v, float* __restrict__ out,
                float* __restrict__ attn)
{
  __shared__ __align__(16) _Float16 kv[UEXT][KV_STRIDE];  // K window, then V
  __shared__ __align__(16) _Float16 kq[TQ][DHEAD];        // Q tile (f16)
  __shared__ __align__(16) _Float16 sc[TQ][SC_STRIDE];    // unnormalized exp scores
  __shared__ float rinv[TQ];

  const int t    = threadIdx.x;
  const int lane = t & 63;
  const int wv   = t >> 6;       // wave 0..3
  const int trow = lane >> 4;    // 0..3
  const int tcol = lane & 15;    // 0..15

  // XCD-chunked swizzle: 4096 blocks = 8 XCDs x 512 contiguous tiles.
  const int blk   = ((blockIdx.x & 7) << 9) + (blockIdx.x >> 3);
  const int bh    = blk >> 7;          // / 128 tiles
  const int i0    = (blk & 127) * TQ;  // first query row of tile
  const int jbase = i0 - 256;          // global key row of staged column u=0

  const size_t base = (size_t)bh * (S_LEN * DHEAD);
  const float* qb = q + base;
  const float* kb = k + base;
  const float* vb = v + base;

  const f4v fzero = {0.f, 0.f, 0.f, 0.f};

  // ---------------- P0: stage Q tile + K window as f16 ----------------
  {
    const int r = t >> 4, d4 = t & 15;
    f4v f = *(const f4v*)(qb + (size_t)(i0 + r) * DHEAD + 4 * d4);
    h4v h = { (_Float16)f.x, (_Float16)f.y, (_Float16)f.z, (_Float16)f.w };
    *(h4v*)&kq[r][4 * d4] = h;
  }
  #pragma unroll 4
  for (int w = 0; w < 17; ++w) {
    const int idx = t + 256 * w;       // 0..4351
    const int u = idx >> 4, d4 = idx & 15;
    const int j = jbase + u;
    f4v f = fzero;                      // zero-fill OOB rows
    if (j >= 0 && j < S_LEN) f = *(const f4v*)(kb + (size_t)j * DHEAD + 4 * d4);
    h4v h = { (_Float16)f.x, (_Float16)f.y, (_Float16)f.z, (_Float16)f.w };
    *(h4v*)&kv[u][4 * d4] = h;
  }
  __syncthreads();

  // ------- P1: QK^T row-split. Wave wv owns rows 4wv..4wv+3; group trow
  // ------- owns one row; lane tcol covers columns u = tcol + 16j. -------
  {
    const int r = 4 * wv + trow;
    f4v qreg[8];
    #pragma unroll
    for (int x = 0; x < 8; ++x) qreg[x] = *(const f4v*)&kq[r][8 * x];

    float rs = 0.f;
    #pragma unroll 4
    for (int j17 = 0; j17 < 17; ++j17) {
      const int u = tcol + 16 * j17;
      float a = 0.f;
      #pragma unroll
      for (int x = 0; x < 8; ++x) {
        const f4v kr = *(const f4v*)&kv[u][8 * x];
        a = dot2f(qreg[x].x, kr.x, a);
        a = dot2f(qreg[x].y, kr.y, a);
        a = dot2f(qreg[x].z, kr.z, a);
        a = dot2f(qreg[x].w, kr.w, a);
      }
      // window: u in [r+1, r+256]; j_global >= 0 <=> u >= 256 - i0
      const bool valid = (u >= r + 1) && (u <= r + 256) && (u >= 256 - i0);
      const float p = valid ? __expf(a * 0.125f) : 0.f;
      sc[r][u] = (_Float16)p;
      rs += p;
    }
    // full row sum lives in the 16-lane group
    #pragma unroll
    for (int off = 8; off; off >>= 1) rs += __shfl_down(rs, off, 64);
    if (tcol == 0) rinv[r] = 1.f / rs;
  }
  __syncthreads();

  // ---------------- P2: stage V (overwrites kv) ----------------
  #pragma unroll 4
  for (int w = 0; w < 17; ++w) {
    const int idx = t + 256 * w;
    const int u = idx >> 4, d4 = idx & 15;
    const int j = jbase + u;
    f4v f = fzero;
    if (j >= 0 && j < S_LEN) f = *(const f4v*)(vb + (size_t)j * DHEAD + 4 * d4);
    h4v h = { (_Float16)f.x, (_Float16)f.y, (_Float16)f.z, (_Float16)f.w };
    *(h4v*)&kv[u][4 * d4] = h;
  }
  __syncthreads();

  // ------- E: zero-region attn stores. Issued now (after the LAST global
  // ------- load consumption) so they drain under P3/P4, which contain no
  // ------- vmcnt waits. 87.5% of attn bytes at ~zero VALU cost. -------
  float* abase = attn + (size_t)(bh * S_LEN + i0) * S_LEN;
  #pragma unroll 8
  for (int w = 0; w < 32; ++w) {
    const int flat = t + 256 * w;      // 0..8191 (16 rows x 512 float4)
    const int r  = flat >> 9;
    const int u4 = flat & 511;
    const int ir = i0 + r;
    const int glo = (ir - 255) >> 2;   // first f4v group touching the band
    const int ghi = ir >> 2;           // last f4v group touching the band
    if (u4 < glo || u4 > ghi)
      __builtin_nontemporal_store(fzero,
          (f4v*)(abase + (size_t)r * S_LEN + 4 * u4));
  }

  // ------- P3: PV. Wave wv owns rows 4wv..4wv+3; trow splits u into 4x68;
  // ------- tcol owns d = 4tcol..4tcol+3. No partials buffer needed. -------
  {
    f4v acc[4];
    #pragma unroll
    for (int i = 0; i < 4; ++i) acc[i] = fzero;
    const int u0 = 68 * trow;

    for (int s = 0; s < 17; ++s) {
      const int ub = u0 + 4 * s;
      h4v ph[4], vh[4];
      #pragma unroll
      for (int i = 0; i < 4; ++i) ph[i] = *(const h4v*)&sc[4 * wv + i][ub];
      #pragma unroll
      for (int e = 0; e < 4; ++e) vh[e] = *(const h4v*)&kv[ub + e][4 * tcol];
      #pragma unroll
      for (int e = 0; e < 4; ++e) {
        const f4v vv = { (float)vh[e].x, (float)vh[e].y,
                         (float)vh[e].z, (float)vh[e].w };
        #pragma unroll
        for (int i = 0; i < 4; ++i) {
          const float p = (float)ph[i][e];
          acc[i].x = fmaf(p, vv.x, acc[i].x);
          acc[i].y = fmaf(p, vv.y, acc[i].y);
          acc[i].z = fmaf(p, vv.z, acc[i].z);
          acc[i].w = fmaf(p, vv.w, acc[i].w);
        }
      }
    }
    // reduce the 4 u-subranges (trow groups) into trow==0 lanes
    #pragma unroll
    for (int i = 0; i < 4; ++i) {
      #pragma unroll
      for (int c = 0; c < 4; ++c) {
        float x = acc[i][c];
        x += __shfl_down(x, 32, 64);
        x += __shfl_down(x, 16, 64);
        acc[i][c] = x;
      }
    }
    if (trow == 0) {
      #pragma unroll
      for (int i = 0; i < 4; ++i) {
        const int r = 4 * wv + i;
        const float inv = rinv[r];
        f4v o = { acc[i].x * inv, acc[i].y * inv,
                  acc[i].z * inv, acc[i].w * inv };
        __builtin_nontemporal_store(o,
            (f4v*)(out + (size_t)(bh * S_LEN + i0 + r) * DHEAD + 4 * tcol));
      }
    }
  }

  // ---------------- P4: banded attn stores only (~65/512 groups/row) --------
  #pragma unroll 4
  for (int w = 0; w < 32; ++w) {
    const int flat = t + 256 * w;
    const int r  = flat >> 9;
    const int u4 = flat & 511;
    const int ir = i0 + r;
    const int glo = (ir - 255) >> 2;
    const int ghi = ir >> 2;
    if (u4 >= glo && u4 <= ghi) {
      const float inv = rinv[r];
      const int j0 = 4 * u4;
      float va[4];
      #pragma unroll
      for (int c = 0; c < 4; ++c) {
        const int jc = j0 + c;
        int u = jc - jbase;
        u = u < 1 ? 1 : (u > 271 ? 271 : u);   // clamp (discarded when OOB)
        const bool in = (jc <= ir) && (jc > ir - 256);
        va[c] = in ? (float)sc[r][u] * inv : 0.f;
      }
      f4v val = { va[0], va[1], va[2], va[3] };
      __builtin_nontemporal_store(val, (f4v*)(abase + (size_t)r * S_LEN + j0));
    }
  }
}

extern "C" void kernel_launch(void* const* d_in, const int* in_sizes, int n_in,
                              void* d_out, int out_size, void* d_ws, size_t ws_size,
                              hipStream_t stream) {
  const float* q = (const float*)d_in[0];
  const float* k = (const float*)d_in[1];
  const float* v = (const float*)d_in[2];
  float* out  = (float*)d_out;
  float* attn = out + (size_t)2 * 16 * 2048 * 64;   // out first, then attn

  dim3 grid(4096), block(256);                      // 32 bh * 128 tiles
  hipLaunchKernelGGL(cwa_kernel, grid, block, 0, stream, q, k, v, out, attn);
}

// Round 2
// 646.997 us; speedup vs baseline: 1.3347x; 1.0532x over previous
//
#include <hip/hip_runtime.h>

// CausalWindowedAttention: B=2,H=16,S=2048,D=64, window=256, temp=8
// Outputs: out [B,H,S,D] fp32, attn [B,H,S,S] fp32 (concatenated in d_out).
//
// R2: TQ 16->32, block 256->512 (8 waves), window extent 288 = 18*16.
//  - LDS 64,384 B -> 2 blocks/CU = 16 waves/CU (was 12): more latency hiding.
//  - Staging traffic + barriers per output row halved (K/V read amp 17x->9x).
//  - Keeps R1: row-split waves (wave wv owns rows 4wv..4wv+3), XCD-chunked
//    swizzle (2048 = 8 x 256, bijective), zero-region attn stores issued
//    after last global-load consumption so they drain under P3/P4 compute.

#define S_LEN 2048
#define DHEAD 64
#define TQ 32
#define UEXT 288      // staged key-column extent: j in [i0-256, i0+32); 18*16
#define KV_STRIDE 72  // halfs; 144 B rows (16B aligned)
#define SC_STRIDE 292 // halfs; 584 B rows (8B aligned, 4-half multiple)

typedef float     f4v __attribute__((ext_vector_type(4)));
typedef _Float16  h2v __attribute__((ext_vector_type(2)));
typedef _Float16  h4v __attribute__((ext_vector_type(4)));

__device__ __forceinline__ float dot2f(float aBits, float bBits, float c) {
#if __has_builtin(__builtin_amdgcn_fdot2)
  return __builtin_amdgcn_fdot2(__builtin_bit_cast(h2v, aBits),
                                __builtin_bit_cast(h2v, bBits), c, false);
#else
  h2v a = __builtin_bit_cast(h2v, aBits);
  h2v b = __builtin_bit_cast(h2v, bBits);
  return c + (float)a.x * (float)b.x + (float)a.y * (float)b.y;
#endif
}

__global__ __launch_bounds__(512, 4)
void cwa_kernel(const float* __restrict__ q, const float* __restrict__ k,
                const float* __restrict__ v, float* __restrict__ out,
                float* __restrict__ attn)
{
  __shared__ __align__(16) _Float16 kv[UEXT][KV_STRIDE];  // K window, then V
  __shared__ __align__(16) _Float16 kq[TQ][DHEAD];        // Q tile (f16)
  __shared__ __align__(16) _Float16 sc[TQ][SC_STRIDE];    // unnormalized exp scores
  __shared__ float rinv[TQ];

  const int t    = threadIdx.x;
  const int lane = t & 63;
  const int wv   = t >> 6;       // wave 0..7
  const int trow = lane >> 4;    // 0..3
  const int tcol = lane & 15;    // 0..15

  // XCD-chunked swizzle: 2048 blocks = 8 XCDs x 256 contiguous tiles.
  const int blk   = ((blockIdx.x & 7) << 8) + (blockIdx.x >> 3);
  const int bh    = blk >> 6;          // / 64 tiles per bh
  const int i0    = (blk & 63) * TQ;   // first query row of tile
  const int jbase = i0 - 256;          // global key row of staged column u=0

  const size_t base = (size_t)bh * (S_LEN * DHEAD);
  const float* qb = q + base;
  const float* kb = k + base;
  const float* vb = v + base;

  const f4v fzero = {0.f, 0.f, 0.f, 0.f};

  // ---------------- P0: stage Q tile + K window as f16 ----------------
  {
    const int r = t >> 4, d4 = t & 15;       // 32 rows x 16 groups = 512
    f4v f = *(const f4v*)(qb + (size_t)(i0 + r) * DHEAD + 4 * d4);
    h4v h = { (_Float16)f.x, (_Float16)f.y, (_Float16)f.z, (_Float16)f.w };
    *(h4v*)&kq[r][4 * d4] = h;
  }
  #pragma unroll 3
  for (int w = 0; w < 9; ++w) {
    const int idx = t + 512 * w;       // 0..4607 (288 rows x 16 groups)
    const int u = idx >> 4, d4 = idx & 15;
    const int j = jbase + u;
    f4v f = fzero;                      // zero-fill OOB rows
    if (j >= 0 && j < S_LEN) f = *(const f4v*)(kb + (size_t)j * DHEAD + 4 * d4);
    h4v h = { (_Float16)f.x, (_Float16)f.y, (_Float16)f.z, (_Float16)f.w };
    *(h4v*)&kv[u][4 * d4] = h;
  }
  __syncthreads();

  // ------- P1: QK^T row-split. Wave wv owns rows 4wv..4wv+3; group trow
  // ------- owns one row; lane tcol covers columns u = tcol + 16j, j<18. ----
  {
    const int r = 4 * wv + trow;
    f4v qreg[8];
    #pragma unroll
    for (int x = 0; x < 8; ++x) qreg[x] = *(const f4v*)&kq[r][8 * x];

    float rs = 0.f;
    #pragma unroll 3
    for (int j18 = 0; j18 < 18; ++j18) {
      const int u = tcol + 16 * j18;
      float a = 0.f;
      #pragma unroll
      for (int x = 0; x < 8; ++x) {
        const f4v kr = *(const f4v*)&kv[u][8 * x];
        a = dot2f(qreg[x].x, kr.x, a);
        a = dot2f(qreg[x].y, kr.y, a);
        a = dot2f(qreg[x].z, kr.z, a);
        a = dot2f(qreg[x].w, kr.w, a);
      }
      // window: u in [r+1, r+256]; j_global >= 0 <=> u >= 256 - i0
      const bool valid = (u >= r + 1) && (u <= r + 256) && (u >= 256 - i0);
      const float p = valid ? __expf(a * 0.125f) : 0.f;
      sc[r][u] = (_Float16)p;
      rs += p;
    }
    // full row sum lives in the 16-lane group
    #pragma unroll
    for (int off = 8; off; off >>= 1) rs += __shfl_down(rs, off, 64);
    if (tcol == 0) rinv[r] = 1.f / rs;
  }
  __syncthreads();

  // ---------------- P2: stage V (overwrites kv) ----------------
  #pragma unroll 3
  for (int w = 0; w < 9; ++w) {
    const int idx = t + 512 * w;
    const int u = idx >> 4, d4 = idx & 15;
    const int j = jbase + u;
    f4v f = fzero;
    if (j >= 0 && j < S_LEN) f = *(const f4v*)(vb + (size_t)j * DHEAD + 4 * d4);
    h4v h = { (_Float16)f.x, (_Float16)f.y, (_Float16)f.z, (_Float16)f.w };
    *(h4v*)&kv[u][4 * d4] = h;
  }
  __syncthreads();

  // ------- E: zero-region attn stores. Issued now (after the LAST global
  // ------- load consumption) so they drain under P3/P4, which contain no
  // ------- vmcnt waits. 87.5% of attn bytes at ~zero VALU cost. -------
  float* abase = attn + (size_t)(bh * S_LEN + i0) * S_LEN;
  #pragma unroll 8
  for (int w = 0; w < 32; ++w) {
    const int flat = t + 512 * w;      // 0..16383 (32 rows x 512 float4)
    const int r  = flat >> 9;
    const int u4 = flat & 511;
    const int ir = i0 + r;
    const int glo = (ir - 255) >> 2;   // first f4v group touching the band
    const int ghi = ir >> 2;           // last f4v group touching the band
    if (u4 < glo || u4 > ghi)
      __builtin_nontemporal_store(fzero,
          (f4v*)(abase + (size_t)r * S_LEN + 4 * u4));
  }

  // ------- P3: PV. Wave wv owns rows 4wv..4wv+3; trow splits u into 4x72;
  // ------- tcol owns d = 4tcol..4tcol+3. -------
  {
    f4v acc[4];
    #pragma unroll
    for (int i = 0; i < 4; ++i) acc[i] = fzero;
    const int u0 = 72 * trow;

    for (int s = 0; s < 18; ++s) {
      const int ub = u0 + 4 * s;
      h4v ph[4], vh[4];
      #pragma unroll
      for (int i = 0; i < 4; ++i) ph[i] = *(const h4v*)&sc[4 * wv + i][ub];
      #pragma unroll
      for (int e = 0; e < 4; ++e) vh[e] = *(const h4v*)&kv[ub + e][4 * tcol];
      #pragma unroll
      for (int e = 0; e < 4; ++e) {
        const f4v vv = { (float)vh[e].x, (float)vh[e].y,
                         (float)vh[e].z, (float)vh[e].w };
        #pragma unroll
        for (int i = 0; i < 4; ++i) {
          const float p = (float)ph[i][e];
          acc[i].x = fmaf(p, vv.x, acc[i].x);
          acc[i].y = fmaf(p, vv.y, acc[i].y);
          acc[i].z = fmaf(p, vv.z, acc[i].z);
          acc[i].w = fmaf(p, vv.w, acc[i].w);
        }
      }
    }
    // reduce the 4 u-subranges (trow groups) into trow==0 lanes
    #pragma unroll
    for (int i = 0; i < 4; ++i) {
      #pragma unroll
      for (int c = 0; c < 4; ++c) {
        float x = acc[i][c];
        x += __shfl_down(x, 32, 64);
        x += __shfl_down(x, 16, 64);
        acc[i][c] = x;
      }
    }
    if (trow == 0) {
      #pragma unroll
      for (int i = 0; i < 4; ++i) {
        const int r = 4 * wv + i;
        const float inv = rinv[r];
        f4v o = { acc[i].x * inv, acc[i].y * inv,
                  acc[i].z * inv, acc[i].w * inv };
        __builtin_nontemporal_store(o,
            (f4v*)(out + (size_t)(bh * S_LEN + i0 + r) * DHEAD + 4 * tcol));
      }
    }
  }

  // ---------------- P4: banded attn stores only (~65/512 groups/row) --------
  #pragma unroll 4
  for (int w = 0; w < 32; ++w) {
    const int flat = t + 512 * w;
    const int r  = flat >> 9;
    const int u4 = flat & 511;
    const int ir = i0 + r;
    const int glo = (ir - 255) >> 2;
    const int ghi = ir >> 2;
    if (u4 >= glo && u4 <= ghi) {
      const float inv = rinv[r];
      const int j0 = 4 * u4;
      float va[4];
      #pragma unroll
      for (int c = 0; c < 4; ++c) {
        const int jc = j0 + c;
        int u = jc - jbase;
        u = u < 1 ? 1 : (u > 287 ? 287 : u);   // clamp (discarded when OOB)
        const bool in = (jc <= ir) && (jc > ir - 256);
        va[c] = in ? (float)sc[r][u] * inv : 0.f;
      }
      f4v val = { va[0], va[1], va[2], va[3] };
      __builtin_nontemporal_store(val, (f4v*)(abase + (size_t)r * S_LEN + j0));
    }
  }
}

extern "C" void kernel_launch(void* const* d_in, const int* in_sizes, int n_in,
                              void* d_out, int out_size, void* d_ws, size_t ws_size,
                              hipStream_t stream) {
  const float* q = (const float*)d_in[0];
  const float* k = (const float*)d_in[1];
  const float* v = (const float*)d_in[2];
  float* out  = (float*)d_out;
  float* attn = out + (size_t)2 * 16 * 2048 * 64;   // out first, then attn

  dim3 grid(2048), block(512);                      // 32 bh * 64 tiles
  hipLaunchKernelGGL(cwa_kernel, grid, block, 0, stream, q, k, v, out, attn);
}

// Round 3
// 612.655 us; speedup vs baseline: 1.4095x; 1.0561x over previous
//
#include <hip/hip_runtime.h>

// CausalWindowedAttention: B=2,H=16,S=2048,D=64, window=256, temp=8
// Outputs: out [B,H,S,D] fp32, attn [B,H,S,S] fp32 (concatenated in d_out).
//
// R3: store-shadow restructure.
//  - Phase order P0,P1,P2, E(zeros), P4(band), P3(PV last): all attn stores
//    issue BEFORE the heaviest compute phase so the store queue drains under
//    P3 (which has no vmem waits), instead of leaking into next block's P0.
//    (vmcnt is in-order: loads consumed after stores stall on store drain,
//    so all global loads still issue/consume before any store.)
//  - P4 vectorized: per-row thread map, one aligned h4v read per group
//    (jbase%4==0 => u0>=0 provably; sc holds exact zeros outside the window,
//    cols 288..291 zero-filled in P1) -> no clamp, no mask, 4x fewer DS ops.
//  - E row-mapped: hoisted per-row constants, ~3 VALU per 16B store.
//  - Keeps R2: TQ=32, 512 thr, UEXT=288, 2 blocks/CU, XCD-chunked swizzle.

#define S_LEN 2048
#define DHEAD 64
#define TQ 32
#define UEXT 288      // staged key-column extent: j in [i0-256, i0+32); 18*16
#define KV_STRIDE 72  // halfs; 144 B rows (16B aligned; 2-way bank alias only)
#define SC_STRIDE 292 // halfs; 584 B rows (8B aligned)

typedef float     f4v __attribute__((ext_vector_type(4)));
typedef _Float16  h2v __attribute__((ext_vector_type(2)));
typedef _Float16  h4v __attribute__((ext_vector_type(4)));

__device__ __forceinline__ float dot2f(float aBits, float bBits, float c) {
#if __has_builtin(__builtin_amdgcn_fdot2)
  return __builtin_amdgcn_fdot2(__builtin_bit_cast(h2v, aBits),
                                __builtin_bit_cast(h2v, bBits), c, false);
#else
  h2v a = __builtin_bit_cast(h2v, aBits);
  h2v b = __builtin_bit_cast(h2v, bBits);
  return c + (float)a.x * (float)b.x + (float)a.y * (float)b.y;
#endif
}

__global__ __launch_bounds__(512, 4)
void cwa_kernel(const float* __restrict__ q, const float* __restrict__ k,
                const float* __restrict__ v, float* __restrict__ out,
                float* __restrict__ attn)
{
  __shared__ __align__(16) _Float16 kv[UEXT][KV_STRIDE];  // K window, then V
  __shared__ __align__(16) _Float16 kq[TQ][DHEAD];        // Q tile (f16)
  __shared__ __align__(16) _Float16 sc[TQ][SC_STRIDE];    // unnormalized exp scores
  __shared__ float rinv[TQ];

  const int t    = threadIdx.x;
  const int lane = t & 63;
  const int wv   = t >> 6;       // wave 0..7
  const int trow = lane >> 4;    // 0..3
  const int tcol = lane & 15;    // 0..15

  // XCD-chunked swizzle: 2048 blocks = 8 XCDs x 256 contiguous tiles.
  const int blk   = ((blockIdx.x & 7) << 8) + (blockIdx.x >> 3);
  const int bh    = blk >> 6;          // / 64 tiles per bh
  const int i0    = (blk & 63) * TQ;   // first query row of tile
  const int jbase = i0 - 256;          // global key row of staged column u=0

  const size_t base = (size_t)bh * (S_LEN * DHEAD);
  const float* qb = q + base;
  const float* kb = k + base;
  const float* vb = v + base;

  const f4v fzero = {0.f, 0.f, 0.f, 0.f};

  // ---------------- P0: stage Q tile + K window as f16 ----------------
  {
    const int r = t >> 4, d4 = t & 15;       // 32 rows x 16 groups = 512
    f4v f = *(const f4v*)(qb + (size_t)(i0 + r) * DHEAD + 4 * d4);
    h4v h = { (_Float16)f.x, (_Float16)f.y, (_Float16)f.z, (_Float16)f.w };
    *(h4v*)&kq[r][4 * d4] = h;
  }
  #pragma unroll 3
  for (int w = 0; w < 9; ++w) {
    const int idx = t + 512 * w;       // 0..4607 (288 rows x 16 groups)
    const int u = idx >> 4, d4 = idx & 15;
    const int j = jbase + u;
    f4v f = fzero;                      // zero-fill OOB rows
    if (j >= 0 && j < S_LEN) f = *(const f4v*)(kb + (size_t)j * DHEAD + 4 * d4);
    h4v h = { (_Float16)f.x, (_Float16)f.y, (_Float16)f.z, (_Float16)f.w };
    *(h4v*)&kv[u][4 * d4] = h;
  }
  __syncthreads();

  // ------- P1: QK^T row-split. Wave wv owns rows 4wv..4wv+3; group trow
  // ------- owns one row; lane tcol covers columns u = tcol + 16j, j<18. ----
  {
    const int r = 4 * wv + trow;
    f4v qreg[8];
    #pragma unroll
    for (int x = 0; x < 8; ++x) qreg[x] = *(const f4v*)&kq[r][8 * x];

    float rs = 0.f;
    #pragma unroll 3
    for (int j18 = 0; j18 < 18; ++j18) {
      const int u = tcol + 16 * j18;
      float a = 0.f;
      #pragma unroll
      for (int x = 0; x < 8; ++x) {
        const f4v kr = *(const f4v*)&kv[u][8 * x];
        a = dot2f(qreg[x].x, kr.x, a);
        a = dot2f(qreg[x].y, kr.y, a);
        a = dot2f(qreg[x].z, kr.z, a);
        a = dot2f(qreg[x].w, kr.w, a);
      }
      // window: u in [r+1, r+256]; j_global >= 0 <=> u >= 256 - i0
      const bool valid = (u >= r + 1) && (u <= r + 256) && (u >= 256 - i0);
      const float p = valid ? __expf(a * 0.125f) : 0.f;
      sc[r][u] = (_Float16)p;
      rs += p;
    }
    // top-edge pad so P4's h4v group reads never see garbage
    if (tcol < 4) sc[r][288 + tcol] = (_Float16)0.f;
    // full row sum lives in the 16-lane group
    #pragma unroll
    for (int off = 8; off; off >>= 1) rs += __shfl_down(rs, off, 64);
    if (tcol == 0) rinv[r] = 1.f / rs;
  }
  __syncthreads();

  // ---------------- P2: stage V (overwrites kv) ----------------
  #pragma unroll 3
  for (int w = 0; w < 9; ++w) {
    const int idx = t + 512 * w;
    const int u = idx >> 4, d4 = idx & 15;
    const int j = jbase + u;
    f4v f = fzero;
    if (j >= 0 && j < S_LEN) f = *(const f4v*)(vb + (size_t)j * DHEAD + 4 * d4);
    h4v h = { (_Float16)f.x, (_Float16)f.y, (_Float16)f.z, (_Float16)f.w };
    *(h4v*)&kv[u][4 * d4] = h;
  }
  __syncthreads();

  // ------- Per-thread row constants for the attn store phases -------
  float* abase = attn + (size_t)(bh * S_LEN + i0) * S_LEN;
  const int er  = t >> 4;            // this thread's attn row (0..31)
  const int eir = i0 + er;
  int glo = (eir - 255) >> 2;  if (glo < 0) glo = 0;   // first band group
  const int ghi = eir >> 2;                            // last band group
  float* erow = abase + (size_t)er * S_LEN;

  // ------- E: zero-region stores (87.5% of attn bytes). Issued after the
  // ------- LAST global-load consumption; drain under P4 issue + all of P3. --
  #pragma unroll 8
  for (int w = 0; w < 32; ++w) {
    const int u4 = tcol + 16 * w;     // 16 lanes sweep contiguous groups
    if (u4 < glo || u4 > ghi)
      __builtin_nontemporal_store(fzero, (f4v*)(erow + 4 * u4));
  }

  // ------- P4: band stores, vectorized. Group base u0 = 4*u4 - jbase is
  // ------- >= 0 and 4-aligned (jbase%4==0); sc is exact-zero outside the
  // ------- window, so no clamp and no element mask needed. -------
  {
    const float inv = rinv[er];
    #pragma unroll
    for (int w = 0; w < 5; ++w) {
      const int u4 = glo + tcol + 16 * w;
      if (u4 <= ghi) {
        const int u0 = 4 * u4 - jbase;
        h4v ph = *(const h4v*)&sc[er][u0];
        f4v val = { (float)ph.x * inv, (float)ph.y * inv,
                    (float)ph.z * inv, (float)ph.w * inv };
        __builtin_nontemporal_store(val, (f4v*)(erow + 4 * u4));
      }
    }
  }

  // ------- P3: PV last (pure LDS+VALU, no vmem waits): the store shadow.
  // ------- Wave wv owns rows 4wv..4wv+3; trow splits u into 4x72;
  // ------- tcol owns d = 4tcol..4tcol+3. -------
  {
    f4v acc[4];
    #pragma unroll
    for (int i = 0; i < 4; ++i) acc[i] = fzero;
    const int u0 = 72 * trow;

    for (int s = 0; s < 18; ++s) {
      const int ub = u0 + 4 * s;
      h4v ph[4], vh[4];
      #pragma unroll
      for (int i = 0; i < 4; ++i) ph[i] = *(const h4v*)&sc[4 * wv + i][ub];
      #pragma unroll
      for (int e = 0; e < 4; ++e) vh[e] = *(const h4v*)&kv[ub + e][4 * tcol];
      #pragma unroll
      for (int e = 0; e < 4; ++e) {
        const f4v vv = { (float)vh[e].x, (float)vh[e].y,
                         (float)vh[e].z, (float)vh[e].w };
        #pragma unroll
        for (int i = 0; i < 4; ++i) {
          const float p = (float)ph[i][e];
          acc[i].x = fmaf(p, vv.x, acc[i].x);
          acc[i].y = fmaf(p, vv.y, acc[i].y);
          acc[i].z = fmaf(p, vv.z, acc[i].z);
          acc[i].w = fmaf(p, vv.w, acc[i].w);
        }
      }
    }
    // reduce the 4 u-subranges (trow groups) into trow==0 lanes
    #pragma unroll
    for (int i = 0; i < 4; ++i) {
      #pragma unroll
      for (int c = 0; c < 4; ++c) {
        float x = acc[i][c];
        x += __shfl_down(x, 32, 64);
        x += __shfl_down(x, 16, 64);
        acc[i][c] = x;
      }
    }
    if (trow == 0) {
      #pragma unroll
      for (int i = 0; i < 4; ++i) {
        const int r = 4 * wv + i;
        const float inv = rinv[r];
        f4v o = { acc[i].x * inv, acc[i].y * inv,
                  acc[i].z * inv, acc[i].w * inv };
        __builtin_nontemporal_store(o,
            (f4v*)(out + (size_t)(bh * S_LEN + i0 + r) * DHEAD + 4 * tcol));
      }
    }
  }
}

extern "C" void kernel_launch(void* const* d_in, const int* in_sizes, int n_in,
                              void* d_out, int out_size, void* d_ws, size_t ws_size,
                              hipStream_t stream) {
  const float* q = (const float*)d_in[0];
  const float* k = (const float*)d_in[1];
  const float* v = (const float*)d_in[2];
  float* out  = (float*)d_out;
  float* attn = out + (size_t)2 * 16 * 2048 * 64;   // out first, then attn

  dim3 grid(2048), block(512);                      // 32 bh * 64 tiles
  hipLaunchKernelGGL(cwa_kernel, grid, block, 0, stream, q, k, v, out, attn);
}

// Round 4
// 609.126 us; speedup vs baseline: 1.4177x; 1.0058x over previous
//
#include <hip/hip_runtime.h>

// CausalWindowedAttention: B=2,H=16,S=2048,D=64, window=256, temp=8
// Outputs: out [B,H,S,D] fp32, attn [B,H,S,S] fp32 (concatenated in d_out).
//
// R4: MFMA restructure (v_mfma_f32_16x16x32_f16 for QK^T and PV).
//  - No K/V/Q LDS staging: fragments load straight from global (L2-hot via
//    XCD-chunked swizzle). Layout safety: A and B f16 fragments share the
//    same lane->(m/n, k-slot) structure, so any consistent bijective k-slot
//    ordering cancels in the dot product; only lane&15=M/N and the verified
//    C/D map (row=(lane>>4)*4+reg, col=lane&15) are assumed.
//  - LDS 65KB -> 19.2KB (sc scores + rowsum partials). ONE barrier/block.
//  - 256 threads / 4 waves; QK^T: wave owns tr=wv>>1, 9 of 18 col-tiles.
//    PV: wave owns 2 of 8 output tiles. K rows clamped to [0,S); garbage
//    only lands in masked columns (QK) or is multiplied by P=0 exact (PV).
//  - Stores (out, attn-zeros, attn-band) at tail, after all global loads
//    are consumed (vmcnt is in-order); 4 resident blocks cover the drain.

#define S_LEN 2048
#define DHEAD 64
#define TQ 32
#define NTC 18        // column tiles of 16 keys: 288-key staged window
#define SC_STRIDE 296 // halfs; 592 B rows (16B-aligned for b128 frag reads)

typedef float    f4v __attribute__((ext_vector_type(4)));
typedef _Float16 h4v __attribute__((ext_vector_type(4)));
typedef _Float16 h8v __attribute__((ext_vector_type(8)));

__device__ __forceinline__ h8v load8h(const float* p) {
  // 8 consecutive f32 -> 8 f16 (one MFMA operand fragment)
  f4v a = *(const f4v*)p;
  f4v b = *(const f4v*)(p + 4);
  h8v h;
  h[0] = (_Float16)a.x; h[1] = (_Float16)a.y;
  h[2] = (_Float16)a.z; h[3] = (_Float16)a.w;
  h[4] = (_Float16)b.x; h[5] = (_Float16)b.y;
  h[6] = (_Float16)b.z; h[7] = (_Float16)b.w;
  return h;
}

__global__ __launch_bounds__(256, 4)
void cwa_kernel(const float* __restrict__ q, const float* __restrict__ k,
                const float* __restrict__ v, float* __restrict__ out,
                float* __restrict__ attn)
{
  __shared__ __align__(16) _Float16 sc[TQ][SC_STRIDE]; // unnormalized exp scores
  __shared__ float rsp[4][16];                         // per-wave rowsum partials

  const int t  = threadIdx.x;
  const int lane = t & 63;
  const int wv = t >> 6;        // wave 0..3
  const int g  = lane >> 4;     // k-slot group 0..3
  const int nl = lane & 15;     // M (A) / N (B) index within 16x16 tile

  // XCD-chunked swizzle: 2048 blocks = 8 XCDs x 256 contiguous tiles.
  const int blk   = ((blockIdx.x & 7) << 8) + (blockIdx.x >> 3);
  const int bh    = blk >> 6;
  const int i0    = (blk & 63) * TQ;   // first query row of tile
  const int jbase = i0 - 256;          // global key row of window column u=0

  const size_t base = (size_t)bh * (S_LEN * DHEAD);
  const float* qb = q + base;
  const float* kb = k + base;
  const float* vb = v + base;

  const f4v fzero = {0.f, 0.f, 0.f, 0.f};

  // ---------------- P1: QK^T via MFMA + mask/exp/rowsum ----------------
  {
    const int tr = wv >> 1;                 // row-block 0..1
    const int qrow = i0 + tr * 16 + nl;     // always in [0, S)
    h8v qf0 = load8h(qb + (size_t)qrow * DHEAD + 8 * g);        // d 0..31 slots
    h8v qf1 = load8h(qb + (size_t)qrow * DHEAD + 32 + 8 * g);   // d 32..63

    float rs0 = 0.f, rs1 = 0.f, rs2 = 0.f, rs3 = 0.f;
    const int tcsub = wv & 1;

    #pragma unroll 3
    for (int kk = 0; kk < 9; ++kk) {
      const int tc = tcsub + 2 * kk;        // this wave's column tiles
      int j = jbase + tc * 16 + nl;         // key row for B-fragment
      j = j < 0 ? 0 : j;                    // clamp (masked later; j<=2047 always)
      const float* krow = kb + (size_t)j * DHEAD;
      h8v kf0 = load8h(krow + 8 * g);
      h8v kf1 = load8h(krow + 32 + 8 * g);
      f4v acc = fzero;
      acc = __builtin_amdgcn_mfma_f32_16x16x32_f16(qf0, kf0, acc, 0, 0, 0);
      acc = __builtin_amdgcn_mfma_f32_16x16x32_f16(qf1, kf1, acc, 0, 0, 0);

      // D layout: row = 4g + reg, col = nl (verified C/D map)
      #pragma unroll
      for (int jj = 0; jj < 4; ++jj) {
        const int r = tr * 16 + 4 * g + jj; // tile-local query row 0..31
        const int u = tc * 16 + nl;         // window-local key col 0..287
        const bool valid = (u >= r + 1) && (u <= r + 256) && (u >= 256 - i0);
        const float p = valid ? __expf(acc[jj] * 0.125f) : 0.f;
        sc[r][u] = (_Float16)p;
        if (jj == 0) rs0 += p; else if (jj == 1) rs1 += p;
        else if (jj == 2) rs2 += p; else rs3 += p;
      }
    }
    // reduce across the 16 columns (nl dimension)
    #pragma unroll
    for (int off = 8; off; off >>= 1) {
      rs0 += __shfl_down(rs0, off, 64);
      rs1 += __shfl_down(rs1, off, 64);
      rs2 += __shfl_down(rs2, off, 64);
      rs3 += __shfl_down(rs3, off, 64);
    }
    if (nl == 0) {
      rsp[wv][4 * g + 0] = rs0;
      rsp[wv][4 * g + 1] = rs1;
      rsp[wv][4 * g + 2] = rs2;
      rsp[wv][4 * g + 3] = rs3;
    }
  }
  __syncthreads();   // sc + rsp ready; the ONLY barrier

  // ---------------- P3: PV via MFMA (V direct from global) ----------------
  {
    const int tr2 = wv >> 1;
    const int nc0 = (wv & 1) * 2;           // this wave's two d-blocks
    f4v pa0 = fzero, pa1 = fzero;

    #pragma unroll 2
    for (int kk = 0; kk < 9; ++kk) {
      const int kb0 = 32 * kk;
      // A-frag: P row = nl, k-slots u = kb0 + 8g + e (contiguous b128)
      h8v pf = *(const h8v*)&sc[tr2 * 16 + nl][kb0 + 8 * g];
      // B-frags: V[u][d], same k-slot map; rows clamped (P=0 kills garbage)
      const int u0 = kb0 + 8 * g;
      h8v vf0, vf1;
      #pragma unroll
      for (int e = 0; e < 8; ++e) {
        int j = jbase + u0 + e;
        j = j < 0 ? 0 : j;
        const float* vrow = vb + (size_t)j * DHEAD + nl;
        vf0[e] = (_Float16)vrow[nc0 * 16];
        vf1[e] = (_Float16)vrow[nc0 * 16 + 16];
      }
      pa0 = __builtin_amdgcn_mfma_f32_16x16x32_f16(pf, vf0, pa0, 0, 0, 0);
      pa1 = __builtin_amdgcn_mfma_f32_16x16x32_f16(pf, vf1, pa1, 0, 0, 0);
    }

    // epilogue: normalize + store out (D row = 4g + reg, col = nl)
    #pragma unroll
    for (int jj = 0; jj < 4; ++jj) {
      const int x = 4 * g + jj;
      const float inv = 1.f / (rsp[2 * tr2][x] + rsp[2 * tr2 + 1][x]);
      const int row = i0 + tr2 * 16 + x;
      float* orow = out + (size_t)(bh * S_LEN + row) * DHEAD + nl;
      __builtin_nontemporal_store(pa0[jj] * inv, orow + nc0 * 16);
      __builtin_nontemporal_store(pa1[jj] * inv, orow + nc0 * 16 + 16);
    }
  }

  // ---------------- Tail: attn stores (zeros + band) ----------------
  float* abase = attn + (size_t)(bh * S_LEN + i0) * S_LEN;
  const int tcol = t & 15;

  #pragma unroll
  for (int pass = 0; pass < 2; ++pass) {
    const int er  = (t >> 4) + 16 * pass;   // attn row 0..31
    const int eir = i0 + er;
    int glo = (eir - 255) >> 2;  if (glo < 0) glo = 0;
    const int ghi = eir >> 2;
    float* erow = abase + (size_t)er * S_LEN;

    // zero region (87.5% of bytes)
    #pragma unroll 8
    for (int w = 0; w < 32; ++w) {
      const int u4 = tcol + 16 * w;
      if (u4 < glo || u4 > ghi)
        __builtin_nontemporal_store(fzero, (f4v*)(erow + 4 * u4));
    }
    // band: u0 = 4*u4 - jbase is >= 0 and 4-aligned; sc==0 outside window
    const float inv = 1.f / (rsp[2 * (er >> 4)][er & 15] +
                             rsp[2 * (er >> 4) + 1][er & 15]);
    #pragma unroll
    for (int w = 0; w < 5; ++w) {
      const int u4 = glo + tcol + 16 * w;
      if (u4 <= ghi) {
        const int u0 = 4 * u4 - jbase;
        h4v ph = *(const h4v*)&sc[er][u0];
        f4v val = { (float)ph.x * inv, (float)ph.y * inv,
                    (float)ph.z * inv, (float)ph.w * inv };
        __builtin_nontemporal_store(val, (f4v*)(erow + 4 * u4));
      }
    }
  }
}

extern "C" void kernel_launch(void* const* d_in, const int* in_sizes, int n_in,
                              void* d_out, int out_size, void* d_ws, size_t ws_size,
                              hipStream_t stream) {
  const float* q = (const float*)d_in[0];
  const float* k = (const float*)d_in[1];
  const float* v = (const float*)d_in[2];
  float* out  = (float*)d_out;
  float* attn = out + (size_t)2 * 16 * 2048 * 64;   // out first, then attn

  dim3 grid(2048), block(256);                      // 32 bh * 64 tiles of 32 rows
  hipLaunchKernelGGL(cwa_kernel, grid, block, 0, stream, q, k, v, out, attn);
}

// Round 5
// 600.246 us; speedup vs baseline: 1.4387x; 1.0148x over previous
//
#include <hip/hip_runtime.h>

// CausalWindowedAttention: B=2,H=16,S=2048,D=64, window=256, temp=8
// Outputs: out [B,H,S,D] fp32, attn [B,H,S,S] fp32 (concatenated in d_out).
//
// R5 = R4 (MFMA, no staging, one barrier) + PLAIN cached stores everywhere.
//  Evidence: fillBufferAligned (plain stores) shows ZERO write amplification
//  (WRITE_SIZE == buffer size) at 6.2-6.4 TB/s on this exact buffer, while
//  our nontemporal 16B stores measured 1.48x WRITE_SIZE amplification
//  (822 MB vs 554 MB ideal). NT bypasses L2 write-combining -> partial-burst
//  HBM writes. Plain stores ride L2 write-back: full 64B lines, no amp.
//
// R4 recap:
//  - v_mfma_f32_16x16x32_f16 for QK^T and PV; fragments straight from global
//    (L2-hot via XCD-chunked swizzle). A/B f16 fragments share the same
//    lane->(m/n, k-slot) structure, so any consistent bijective k-slot
//    ordering cancels; C/D map row=(lane>>4)*4+reg, col=lane&15 (verified).
//  - LDS 19.2KB (sc + rowsum partials). ONE barrier per block.
//  - K rows clamped to [0,S); garbage lands only in masked cols (QK) or is
//    multiplied by exact P=0 (PV).

#define S_LEN 2048
#define DHEAD 64
#define TQ 32
#define NTC 18        // column tiles of 16 keys: 288-key window
#define SC_STRIDE 296 // halfs; 592 B rows (16B-aligned for b128 frag reads)

typedef float    f4v __attribute__((ext_vector_type(4)));
typedef _Float16 h4v __attribute__((ext_vector_type(4)));
typedef _Float16 h8v __attribute__((ext_vector_type(8)));

__device__ __forceinline__ h8v load8h(const float* p) {
  // 8 consecutive f32 -> 8 f16 (one MFMA operand fragment)
  f4v a = *(const f4v*)p;
  f4v b = *(const f4v*)(p + 4);
  h8v h;
  h[0] = (_Float16)a.x; h[1] = (_Float16)a.y;
  h[2] = (_Float16)a.z; h[3] = (_Float16)a.w;
  h[4] = (_Float16)b.x; h[5] = (_Float16)b.y;
  h[6] = (_Float16)b.z; h[7] = (_Float16)b.w;
  return h;
}

__global__ __launch_bounds__(256, 4)
void cwa_kernel(const float* __restrict__ q, const float* __restrict__ k,
                const float* __restrict__ v, float* __restrict__ out,
                float* __restrict__ attn)
{
  __shared__ __align__(16) _Float16 sc[TQ][SC_STRIDE]; // unnormalized exp scores
  __shared__ float rsp[4][16];                         // per-wave rowsum partials

  const int t  = threadIdx.x;
  const int lane = t & 63;
  const int wv = t >> 6;        // wave 0..3
  const int g  = lane >> 4;     // k-slot group 0..3
  const int nl = lane & 15;     // M (A) / N (B) index within 16x16 tile

  // XCD-chunked swizzle: 2048 blocks = 8 XCDs x 256 contiguous tiles.
  const int blk   = ((blockIdx.x & 7) << 8) + (blockIdx.x >> 3);
  const int bh    = blk >> 6;
  const int i0    = (blk & 63) * TQ;   // first query row of tile
  const int jbase = i0 - 256;          // global key row of window column u=0

  const size_t base = (size_t)bh * (S_LEN * DHEAD);
  const float* qb = q + base;
  const float* kb = k + base;
  const float* vb = v + base;

  const f4v fzero = {0.f, 0.f, 0.f, 0.f};

  // ---------------- P1: QK^T via MFMA + mask/exp/rowsum ----------------
  {
    const int tr = wv >> 1;                 // row-block 0..1
    const int qrow = i0 + tr * 16 + nl;     // always in [0, S)
    h8v qf0 = load8h(qb + (size_t)qrow * DHEAD + 8 * g);        // d 0..31 slots
    h8v qf1 = load8h(qb + (size_t)qrow * DHEAD + 32 + 8 * g);   // d 32..63

    float rs0 = 0.f, rs1 = 0.f, rs2 = 0.f, rs3 = 0.f;
    const int tcsub = wv & 1;

    #pragma unroll 3
    for (int kk = 0; kk < 9; ++kk) {
      const int tc = tcsub + 2 * kk;        // this wave's column tiles
      int j = jbase + tc * 16 + nl;         // key row for B-fragment
      j = j < 0 ? 0 : j;                    // clamp (masked later; j<=2047 always)
      const float* krow = kb + (size_t)j * DHEAD;
      h8v kf0 = load8h(krow + 8 * g);
      h8v kf1 = load8h(krow + 32 + 8 * g);
      f4v acc = fzero;
      acc = __builtin_amdgcn_mfma_f32_16x16x32_f16(qf0, kf0, acc, 0, 0, 0);
      acc = __builtin_amdgcn_mfma_f32_16x16x32_f16(qf1, kf1, acc, 0, 0, 0);

      // D layout: row = 4g + reg, col = nl (verified C/D map)
      #pragma unroll
      for (int jj = 0; jj < 4; ++jj) {
        const int r = tr * 16 + 4 * g + jj; // tile-local query row 0..31
        const int u = tc * 16 + nl;         // window-local key col 0..287
        const bool valid = (u >= r + 1) && (u <= r + 256) && (u >= 256 - i0);
        const float p = valid ? __expf(acc[jj] * 0.125f) : 0.f;
        sc[r][u] = (_Float16)p;
        if (jj == 0) rs0 += p; else if (jj == 1) rs1 += p;
        else if (jj == 2) rs2 += p; else rs3 += p;
      }
    }
    // reduce across the 16 columns (nl dimension)
    #pragma unroll
    for (int off = 8; off; off >>= 1) {
      rs0 += __shfl_down(rs0, off, 64);
      rs1 += __shfl_down(rs1, off, 64);
      rs2 += __shfl_down(rs2, off, 64);
      rs3 += __shfl_down(rs3, off, 64);
    }
    if (nl == 0) {
      rsp[wv][4 * g + 0] = rs0;
      rsp[wv][4 * g + 1] = rs1;
      rsp[wv][4 * g + 2] = rs2;
      rsp[wv][4 * g + 3] = rs3;
    }
  }
  __syncthreads();   // sc + rsp ready; the ONLY barrier

  // ---------------- P3: PV via MFMA (V direct from global) ----------------
  {
    const int tr2 = wv >> 1;
    const int nc0 = (wv & 1) * 2;           // this wave's two d-blocks
    f4v pa0 = fzero, pa1 = fzero;

    #pragma unroll 2
    for (int kk = 0; kk < 9; ++kk) {
      const int kb0 = 32 * kk;
      // A-frag: P row = nl, k-slots u = kb0 + 8g + e (contiguous b128)
      h8v pf = *(const h8v*)&sc[tr2 * 16 + nl][kb0 + 8 * g];
      // B-frags: V[u][d], same k-slot map; rows clamped (P=0 kills garbage)
      const int u0 = kb0 + 8 * g;
      h8v vf0, vf1;
      #pragma unroll
      for (int e = 0; e < 8; ++e) {
        int j = jbase + u0 + e;
        j = j < 0 ? 0 : j;
        const float* vrow = vb + (size_t)j * DHEAD + nl;
        vf0[e] = (_Float16)vrow[nc0 * 16];
        vf1[e] = (_Float16)vrow[nc0 * 16 + 16];
      }
      pa0 = __builtin_amdgcn_mfma_f32_16x16x32_f16(pf, vf0, pa0, 0, 0, 0);
      pa1 = __builtin_amdgcn_mfma_f32_16x16x32_f16(pf, vf1, pa1, 0, 0, 0);
    }

    // epilogue: normalize + store out (D row = 4g + reg, col = nl)
    #pragma unroll
    for (int jj = 0; jj < 4; ++jj) {
      const int x = 4 * g + jj;
      const float inv = 1.f / (rsp[2 * tr2][x] + rsp[2 * tr2 + 1][x]);
      const int row = i0 + tr2 * 16 + x;
      float* orow = out + (size_t)(bh * S_LEN + row) * DHEAD + nl;
      orow[nc0 * 16]      = pa0[jj] * inv;
      orow[nc0 * 16 + 16] = pa1[jj] * inv;
    }
  }

  // ---------------- Tail: attn stores (zeros + band), plain cached --------
  float* abase = attn + (size_t)(bh * S_LEN + i0) * S_LEN;
  const int tcol = t & 15;

  #pragma unroll
  for (int pass = 0; pass < 2; ++pass) {
    const int er  = (t >> 4) + 16 * pass;   // attn row 0..31
    const int eir = i0 + er;
    int glo = (eir - 255) >> 2;  if (glo < 0) glo = 0;
    const int ghi = eir >> 2;
    float* erow = abase + (size_t)er * S_LEN;

    // zero region (87.5% of bytes)
    #pragma unroll 8
    for (int w = 0; w < 32; ++w) {
      const int u4 = tcol + 16 * w;
      if (u4 < glo || u4 > ghi)
        *(f4v*)(erow + 4 * u4) = fzero;
    }
    // band: u0 = 4*u4 - jbase is >= 0 and 4-aligned; sc==0 outside window
    const float inv = 1.f / (rsp[2 * (er >> 4)][er & 15] +
                             rsp[2 * (er >> 4) + 1][er & 15]);
    #pragma unroll
    for (int w = 0; w < 5; ++w) {
      const int u4 = glo + tcol + 16 * w;
      if (u4 <= ghi) {
        const int u0 = 4 * u4 - jbase;
        h4v ph = *(const h4v*)&sc[er][u0];
        f4v val = { (float)ph.x * inv, (float)ph.y * inv,
                    (float)ph.z * inv, (float)ph.w * inv };
        *(f4v*)(erow + 4 * u4) = val;
      }
    }
  }
}

extern "C" void kernel_launch(void* const* d_in, const int* in_sizes, int n_in,
                              void* d_out, int out_size, void* d_ws, size_t ws_size,
                              hipStream_t stream) {
  const float* q = (const float*)d_in[0];
  const float* k = (const float*)d_in[1];
  const float* v = (const float*)d_in[2];
  float* out  = (float*)d_out;
  float* attn = out + (size_t)2 * 16 * 2048 * 64;   // out first, then attn

  dim3 grid(2048), block(256);                      // 32 bh * 64 tiles of 32 rows
  hipLaunchKernelGGL(cwa_kernel, grid, block, 0, stream, q, k, v, out, attn);
}